// Round 3
// baseline (381.838 us; speedup 1.0000x reference)
//
#include <hip/hip_runtime.h>
#include <hip/hip_bf16.h>

typedef short s16x8 __attribute__((ext_vector_type(8)));
typedef float f32x4 __attribute__((ext_vector_type(4)));

#define B_ 16
#define L_ 2048
#define D_ 64
#define V_ELEMS (B_ * L_ * D_)   // 2,097,152 elements per [B,L,D] tensor

// ---- bf16 helpers (values are finite; no NaN handling needed) ----
__device__ __forceinline__ unsigned rne1(float f) {
    unsigned u = __builtin_bit_cast(unsigned, f);
    return (u + 0x7FFFu + ((u >> 16) & 1u)) >> 16;   // RNE f32->bf16 bits
}
__device__ __forceinline__ unsigned pack2(float a, float b) {
    return (rne1(a) & 0xFFFFu) | (rne1(b) << 16);
}

// Split f32 -> hi (truncated bf16, exact in fp32) + lo (RNE bf16 of residual).
// hi + lo reproduces x to ~2^-15 relative.
__device__ __forceinline__ void split8(float4 a, float4 b, s16x8& hi, s16x8& lo) {
    float f[8] = {a.x, a.y, a.z, a.w, b.x, b.y, b.z, b.w};
    s16x8 h, l;
#pragma unroll
    for (int i = 0; i < 8; ++i) {
        unsigned u = __builtin_bit_cast(unsigned, f[i]);
        h[i] = (short)(u >> 16);
        float lf = f[i] - __builtin_bit_cast(float, u & 0xFFFF0000u);
        l[i] = (short)rne1(lf);
    }
    hi = h; lo = l;
}

// ---- Output 0: v fp32 -> fp32 straight copy ----
__global__ void copy_v_kernel(const float4* __restrict__ v, float4* __restrict__ o) {
    int i = blockIdx.x * blockDim.x + threadIdx.x;   // grid covers V_ELEMS/4
    o[i] = v[i];
}

// ---- prep: split q,k into hi/lo bf16 planes in workspace ----
__global__ void prep_qk_kernel(const float4* __restrict__ q, const float4* __restrict__ k,
                               uint2* __restrict__ qhi, uint2* __restrict__ qlo,
                               uint2* __restrict__ khi, uint2* __restrict__ klo) {
    int i = blockIdx.x * blockDim.x + threadIdx.x;   // grid covers V_ELEMS/4
    float4 fq = q[i];
    float4 fk = k[i];
    unsigned u0 = __builtin_bit_cast(unsigned, fq.x), u1 = __builtin_bit_cast(unsigned, fq.y);
    unsigned u2 = __builtin_bit_cast(unsigned, fq.z), u3 = __builtin_bit_cast(unsigned, fq.w);
    qhi[i] = make_uint2((u0 >> 16) | (u1 & 0xFFFF0000u), (u2 >> 16) | (u3 & 0xFFFF0000u));
    qlo[i] = make_uint2(
        pack2(fq.x - __builtin_bit_cast(float, u0 & 0xFFFF0000u),
              fq.y - __builtin_bit_cast(float, u1 & 0xFFFF0000u)),
        pack2(fq.z - __builtin_bit_cast(float, u2 & 0xFFFF0000u),
              fq.w - __builtin_bit_cast(float, u3 & 0xFFFF0000u)));
    u0 = __builtin_bit_cast(unsigned, fk.x); u1 = __builtin_bit_cast(unsigned, fk.y);
    u2 = __builtin_bit_cast(unsigned, fk.z); u3 = __builtin_bit_cast(unsigned, fk.w);
    khi[i] = make_uint2((u0 >> 16) | (u1 & 0xFFFF0000u), (u2 >> 16) | (u3 & 0xFFFF0000u));
    klo[i] = make_uint2(
        pack2(fk.x - __builtin_bit_cast(float, u0 & 0xFFFF0000u),
              fk.y - __builtin_bit_cast(float, u1 & 0xFFFF0000u)),
        pack2(fk.z - __builtin_bit_cast(float, u2 & 0xFFFF0000u),
              fk.w - __builtin_bit_cast(float, u3 & 0xFFFF0000u)));
}

__device__ __forceinline__ void store4f(float* p, unsigned u0, unsigned u1, float inv) {
    float4 w;
    w.x = __builtin_bit_cast(float, u0 << 16) * inv;
    w.y = __builtin_bit_cast(float, u0 & 0xFFFF0000u) * inv;
    w.z = __builtin_bit_cast(float, u1 << 16) * inv;
    w.w = __builtin_bit_cast(float, u1 & 0xFFFF0000u) * inv;
    *(float4*)p = w;
}

// ---- attention: block = (batch, 32 q-rows); 4 waves x 512-wide k strips.
// bf16x3 MFMA (hi*hi + hi*lo + lo*hi) -> fp32 scores accurate to ~1e-3 abs.
// Single pass over k: exp -> stash packed bf16 + fp32 row-sum -> normalize ->
// fp32 store. No max-subtraction: |score| <~ 50, exp fits fp32 easily.
template <bool PRE>
__global__ __launch_bounds__(256, 2) void attn_kernel(
    const float* __restrict__ qf, const float* __restrict__ kf,
    const ushort* __restrict__ qhi, const ushort* __restrict__ qlo,
    const ushort* __restrict__ khi, const ushort* __restrict__ klo,
    float* __restrict__ og) {
    const int b    = blockIdx.x >> 6;          // 64 q-tiles (of 32 rows) per batch
    const int q0   = (blockIdx.x & 63) << 5;   // first of 32 q rows
    const int tid  = threadIdx.x;
    const int wave = tid >> 6;
    const int lane = tid & 63;
    const int nq   = lane & 15;
    const int quad = lane >> 4;

    // B operand (q): two 16-row tiles, K(=d) split into halves of 32.
    // Layout: [n = lane&15][k = quad*8 + j]
    s16x8 bhi[2][2], blo[2][2];
#pragma unroll
    for (int t = 0; t < 2; ++t) {
        const size_t off = ((size_t)(b * L_ + q0 + t * 16 + nq)) * D_ + quad * 8;
        if constexpr (PRE) {
            bhi[t][0] = *(const s16x8*)(qhi + off);
            bhi[t][1] = *(const s16x8*)(qhi + off + 32);
            blo[t][0] = *(const s16x8*)(qlo + off);
            blo[t][1] = *(const s16x8*)(qlo + off + 32);
        } else {
            float4 a0 = *(const float4*)(qf + off), a1 = *(const float4*)(qf + off + 4);
            float4 a2 = *(const float4*)(qf + off + 32), a3 = *(const float4*)(qf + off + 36);
            split8(a0, a1, bhi[t][0], blo[t][0]);
            split8(a2, a3, bhi[t][1], blo[t][1]);
        }
    }

    const size_t krow0 = (size_t)b * L_ + (size_t)wave * 512 + nq;
    float s0 = 0.0f, s1 = 0.0f;
    unsigned pk0[64], pk1[64];   // 32 subtiles x 4 exps packed into 2 dwords, per q-tile

#pragma unroll
    for (int t = 0; t < 32; ++t) {
        const size_t off = (krow0 + (size_t)t * 16) * D_ + quad * 8;
        s16x8 ahi0, ahi1, alo0, alo1;
        if constexpr (PRE) {
            ahi0 = *(const s16x8*)(khi + off);
            ahi1 = *(const s16x8*)(khi + off + 32);
            alo0 = *(const s16x8*)(klo + off);
            alo1 = *(const s16x8*)(klo + off + 32);
        } else {
            float4 a0 = *(const float4*)(kf + off), a1 = *(const float4*)(kf + off + 4);
            float4 a2 = *(const float4*)(kf + off + 32), a3 = *(const float4*)(kf + off + 36);
            split8(a0, a1, ahi0, alo0);
            split8(a2, a3, ahi1, alo1);
        }
        f32x4 c0 = {0.f, 0.f, 0.f, 0.f}, c1 = {0.f, 0.f, 0.f, 0.f};
        c0 = __builtin_amdgcn_mfma_f32_16x16x32_bf16(ahi0, bhi[0][0], c0, 0, 0, 0);
        c0 = __builtin_amdgcn_mfma_f32_16x16x32_bf16(ahi1, bhi[0][1], c0, 0, 0, 0);
        c0 = __builtin_amdgcn_mfma_f32_16x16x32_bf16(ahi0, blo[0][0], c0, 0, 0, 0);
        c0 = __builtin_amdgcn_mfma_f32_16x16x32_bf16(ahi1, blo[0][1], c0, 0, 0, 0);
        c0 = __builtin_amdgcn_mfma_f32_16x16x32_bf16(alo0, bhi[0][0], c0, 0, 0, 0);
        c0 = __builtin_amdgcn_mfma_f32_16x16x32_bf16(alo1, bhi[0][1], c0, 0, 0, 0);
        c1 = __builtin_amdgcn_mfma_f32_16x16x32_bf16(ahi0, bhi[1][0], c1, 0, 0, 0);
        c1 = __builtin_amdgcn_mfma_f32_16x16x32_bf16(ahi1, bhi[1][1], c1, 0, 0, 0);
        c1 = __builtin_amdgcn_mfma_f32_16x16x32_bf16(ahi0, blo[1][0], c1, 0, 0, 0);
        c1 = __builtin_amdgcn_mfma_f32_16x16x32_bf16(ahi1, blo[1][1], c1, 0, 0, 0);
        c1 = __builtin_amdgcn_mfma_f32_16x16x32_bf16(alo0, bhi[1][0], c1, 0, 0, 0);
        c1 = __builtin_amdgcn_mfma_f32_16x16x32_bf16(alo1, bhi[1][1], c1, 0, 0, 0);
        // c[reg] = score(q = q0 + tile*16 + nq, k = wave*512 + t*16 + quad*4 + reg)
        float e0 = __expf(c0[0]), e1 = __expf(c0[1]), e2 = __expf(c0[2]), e3 = __expf(c0[3]);
        s0 += (e0 + e1) + (e2 + e3);
        pk0[2 * t]     = pack2(e0, e1);
        pk0[2 * t + 1] = pack2(e2, e3);
        float g0 = __expf(c1[0]), g1 = __expf(c1[1]), g2 = __expf(c1[2]), g3 = __expf(c1[3]);
        s1 += (g0 + g1) + (g2 + g3);
        pk1[2 * t]     = pack2(g0, g1);
        pk1[2 * t + 1] = pack2(g2, g3);
    }

    // Row sums: reduce across quads, then across waves via LDS.
    s0 += __shfl_xor(s0, 16); s0 += __shfl_xor(s0, 32);
    s1 += __shfl_xor(s1, 16); s1 += __shfl_xor(s1, 32);
    __shared__ float wsum[4][2][16];
    if (lane < 16) { wsum[wave][0][lane] = s0; wsum[wave][1][lane] = s1; }
    __syncthreads();
    const float inv0 = 1.0f / ((wsum[0][0][nq] + wsum[1][0][nq]) + (wsum[2][0][nq] + wsum[3][0][nq]));
    const float inv1 = 1.0f / ((wsum[0][1][nq] + wsum[1][1][nq]) + (wsum[2][1][nq] + wsum[3][1][nq]));

    float* op0 = og + ((size_t)(b * L_ + q0 + nq)) * L_ + wave * 512 + quad * 4;
    float* op1 = op0 + (size_t)16 * L_;
#pragma unroll
    for (int t = 0; t < 32; ++t) {
        store4f(op0, pk0[2 * t], pk0[2 * t + 1], inv0); op0 += 16;
        store4f(op1, pk1[2 * t], pk1[2 * t + 1], inv1); op1 += 16;
    }
}

extern "C" void kernel_launch(void* const* d_in, const int* in_sizes, int n_in,
                              void* d_out, int out_size, void* d_ws, size_t ws_size,
                              hipStream_t stream) {
    const float* q = (const float*)d_in[0];
    const float* k = (const float*)d_in[1];
    const float* v = (const float*)d_in[2];
    float* out = (float*)d_out;

    // Output 0: v passthrough, fp32 -> fp32, 2,097,152 elements (8 MiB).
    copy_v_kernel<<<dim3(V_ELEMS / 4 / 256), dim3(256), 0, stream>>>(
        (const float4*)v, (float4*)out);

    // Output 1: attention [B, L, L] fp32 (256 MiB).
    float* att = out + (size_t)V_ELEMS;
    const size_t plane = (size_t)V_ELEMS;                  // elements per bf16 plane
    const size_t need  = 4 * plane * sizeof(ushort);       // qhi,qlo,khi,klo = 16 MiB
    ushort* qhi = (ushort*)d_ws;
    ushort* qlo = qhi + plane;
    ushort* khi = qlo + plane;
    ushort* klo = khi + plane;

    if (ws_size >= need) {
        prep_qk_kernel<<<dim3(V_ELEMS / 4 / 256), dim3(256), 0, stream>>>(
            (const float4*)q, (const float4*)k,
            (uint2*)qhi, (uint2*)qlo, (uint2*)khi, (uint2*)klo);
        attn_kernel<true><<<dim3(B_ * (L_ / 32)), dim3(256), 0, stream>>>(
            q, k, qhi, qlo, khi, klo, att);
    } else {
        attn_kernel<false><<<dim3(B_ * (L_ / 32)), dim3(256), 0, stream>>>(
            q, k, qhi, qlo, khi, klo, att);
    }
}